// Round 22
// baseline (51.112 us; speedup 1.0000x reference)
//
#include <hip/hip_runtime.h>
#include <hip/hip_bf16.h>

#define B 16
#define S 4096
#define D 256
#define U 256
#define ROWS 64    // rows per block in score kernel
#define NCHK (S / ROWS)  // 64 chunks per batch

typedef short short8 __attribute__((ext_vector_type(8)));
typedef float f32x4 __attribute__((ext_vector_type(4)));

__device__ __forceinline__ ushort f2bf(float f) {
    union { float f; uint u; } x{f};
    uint r = (x.u + 0x7fffu + ((x.u >> 16) & 1u)) >> 16;  // RNE
    return (ushort)r;
}

__device__ __forceinline__ float fast_tanh(float x) {
    float e = __expf(2.0f * x);
    return 1.0f - 2.0f * __builtin_amdgcn_rcpf(e + 1.0f);
}

// KA: W1 pack only (8 blocks, one kk each) — pq moved into KB per-wave.
__global__ void ka_pack(const float* __restrict__ W1, ushort* __restrict__ W1p) {
    int kk = blockIdx.x, t = threadIdx.x;
    int l = t & 63, g = t >> 6;
    int colu0 = l & 15;
    int k0 = kk * 32 + (l >> 4) * 8;
#pragma unroll
    for (int i = 0; i < 4; ++i) {
        int nt = g * 4 + i;
        int colu = nt * 16 + colu0;
        ushort* dst = W1p + (((nt * 8) + kk) * 64 + l) * 8;
#pragma unroll
        for (int e = 0; e < 8; ++e) dst[e] = f2bf(W1[(k0 + e) * U + colu]);
    }
}

// KB: r13 champion core, with the pq GEMV folded in per-wave: lane l of wave w
// computes pq(u = w*64+l) during the staging bubble (identical summation order
// to the old ka pq -> bit-identical values); epilogue reads bb[nt] via __shfl.
__global__ __launch_bounds__(256, 4) void kb_scores(
    const float* __restrict__ values, const ushort* __restrict__ W1p,
    const float* __restrict__ query, const float* __restrict__ W2,
    const float* __restrict__ b2, const float* __restrict__ b1,
    const float* __restrict__ V, const float* __restrict__ bV,
    float* __restrict__ scores, float* __restrict__ cstats,
    float* __restrict__ cpart) {
    __shared__ ushort Alds[ROWS * 256];  // 32 KB, XOR-swizzled bf16 tile
    __shared__ float red[4][ROWS];
    __shared__ float wch[ROWS];
    int b = blockIdx.x >> 6;
    int s0 = (blockIdx.x & 63) * ROWS;
    int t = threadIdx.x;
    int w = t >> 6, l = t & 63;
    char* lds = (char*)Alds;

    // ---- stage 64x256 fp32 -> bf16 LDS, byte ^= (row&7)<<4 ----
    const float* src = values + ((size_t)(b * S + s0)) * D;
    float4 vreg[16];
#pragma unroll
    for (int i = 0; i < 16; ++i)
        vreg[i] = *(const float4*)&src[(i * 4 + w) * 256 + l * 4];
#pragma unroll
    for (int i = 0; i < 16; ++i) {
        int row = i * 4 + w;
        int col = l * 4;
        ushort4 h;
        h.x = f2bf(vreg[i].x); h.y = f2bf(vreg[i].y);
        h.z = f2bf(vreg[i].z); h.w = f2bf(vreg[i].w);
        int byte = (row * 512 + col * 2) ^ ((row & 7) << 4);
        *(ushort4*)(lds + byte) = h;
    }

    // ---- per-wave pq: lane l owns u = w*64 + l (overlaps staging bubble) ----
    const int upq = w * 64 + l;
    const float* qb = query + b * D;
    float pq = b2[upq] + b1[upq];
#pragma unroll 8
    for (int d = 0; d < D; ++d)
        pq = fmaf(qb[d], W2[d * U + upq], pq);
    __syncthreads();

    // ---- MFMA scores (kk fully unrolled) ----
    int lrow = l & 15, lk = l >> 4;
    f32x4 acc[4][4];
#pragma unroll
    for (int mt = 0; mt < 4; ++mt)
#pragma unroll
        for (int nt = 0; nt < 4; ++nt) acc[mt][nt] = (f32x4){0.f, 0.f, 0.f, 0.f};

#pragma unroll
    for (int kk = 0; kk < 8; ++kk) {
        short8 afr[4], bfr[4];
#pragma unroll
        for (int nt = 0; nt < 4; ++nt) {
            int ntile = w * 4 + nt;
            bfr[nt] = *(const short8*)&W1p[(((ntile * 8) + kk) * 64 + l) * 8];
        }
#pragma unroll
        for (int mt = 0; mt < 4; ++mt) {
            int row = mt * 16 + lrow;
            int byte = (row * 512 + kk * 64 + lk * 16) ^ ((row & 7) << 4);
            afr[mt] = *(const short8*)(lds + byte);
        }
#pragma unroll
        for (int mt = 0; mt < 4; ++mt)
#pragma unroll
            for (int nt = 0; nt < 4; ++nt)
                acc[mt][nt] = __builtin_amdgcn_mfma_f32_16x16x32_bf16(
                    afr[mt], bfr[nt], acc[mt][nt], 0, 0, 0);
    }

    // ---- epilogue: tanh, .V, reduce over u ----
    float bb[4], vv[4];
#pragma unroll
    for (int nt = 0; nt < 4; ++nt) {
        bb[nt] = __shfl(pq, nt * 16 + lrow, 64);  // lane nt*16+lrow holds that u
        vv[nt] = V[(w * 4 + nt) * 16 + lrow];
    }
#pragma unroll
    for (int mt = 0; mt < 4; ++mt) {
#pragma unroll
        for (int r = 0; r < 4; ++r) {
            float s = 0.f;
#pragma unroll
            for (int nt = 0; nt < 4; ++nt)
                s += fast_tanh(acc[mt][nt][r] + bb[nt]) * vv[nt];
            s += __shfl_xor(s, 1);
            s += __shfl_xor(s, 2);
            s += __shfl_xor(s, 4);
            s += __shfl_xor(s, 8);
            if (lrow == 0) red[w][mt * 16 + lk * 4 + r] = s;
        }
    }
    __syncthreads();
    if (t < ROWS) {  // wave 0
        float s = red[0][t] + red[1][t] + red[2][t] + red[3][t] + bV[0];
        scores[b * S + s0 + t] = s;
        float m = s;
#pragma unroll
        for (int off = 32; off; off >>= 1) m = fmaxf(m, __shfl_xor(m, off));
        float z0 = __expf(s - m);
        wch[t] = z0;
        float z = z0;
#pragma unroll
        for (int off = 32; off; off >>= 1) z += __shfl_xor(z, off);
        if (t == 0) {
            cstats[2 * blockIdx.x] = m;
            cstats[2 * blockIdx.x + 1] = z;
        }
    }
    __syncthreads();

    // partial context from the bf16 LDS copy: thread t owns column t.
    union { uint i; float f; } cv;
    float cacc = 0.f;
#pragma unroll 8
    for (int r = 0; r < ROWS; ++r) {
        int byte = (r * 512 + t * 2) ^ ((r & 7) << 4);
        ushort u = *(const ushort*)(lds + byte);
        cv.i = (uint)u << 16;
        cacc = fmaf(wch[r], cv.f, cacc);
    }
    cpart[(size_t)blockIdx.x * D + t] = cacc;
}

// KC: finisher. 4 blocks per batch (q = quarter). (r13 verbatim)
__global__ void kc_final(const float* __restrict__ scores, const float* __restrict__ cstats,
                         const float* __restrict__ cpart, float* __restrict__ wout,
                         float* __restrict__ ctx) {
    __shared__ float scl[NCHK];
    __shared__ float stats[2];
    __shared__ float part[4][64];
    int b = blockIdx.x >> 2, q = blockIdx.x & 3;
    int t = threadIdx.x;

    if (t < 64) {
        float m = cstats[2 * (b * NCHK + t)];
        float z = cstats[2 * (b * NCHK + t) + 1];
        float M = m;
#pragma unroll
        for (int off = 32; off; off >>= 1) M = fmaxf(M, __shfl_xor(M, off));
        float zz = z * __expf(m - M);
#pragma unroll
        for (int off = 32; off; off >>= 1) zz += __shfl_xor(zz, off);
        scl[t] = __expf(m - M);
        if (t == 0) { stats[0] = M; stats[1] = zz; }
    }
    __syncthreads();
    float M = stats[0];
    float invZ = 1.0f / stats[1];

    int tq = t >> 6, dl = t & 63;
    int d = q * 64 + dl;
    float acc = 0.f;
#pragma unroll
    for (int i = 0; i < 16; ++i) {
        int c = tq * 16 + i;
        acc = fmaf(scl[c], cpart[(size_t)(b * NCHK + c) * D + d], acc);
    }
    part[tq][dl] = acc;

#pragma unroll
    for (int i = 0; i < 4; ++i) {
        int s = q * 1024 + i * 256 + t;
        wout[b * S + s] = __expf(scores[b * S + s] - M) * invZ;
    }
    __syncthreads();
    if (t < 64)
        ctx[b * D + q * 64 + t] =
            (part[0][t] + part[1][t] + part[2][t] + part[3][t]) * invZ;
}

extern "C" void kernel_launch(void* const* d_in, const int* in_sizes, int n_in,
                              void* d_out, int out_size, void* d_ws, size_t ws_size,
                              hipStream_t stream) {
    const float* values = (const float*)d_in[0];
    const float* query  = (const float*)d_in[1];
    const float* W1     = (const float*)d_in[2];
    const float* b1     = (const float*)d_in[3];
    const float* W2     = (const float*)d_in[4];
    const float* b2     = (const float*)d_in[5];
    const float* V      = (const float*)d_in[6];
    const float* bV     = (const float*)d_in[7];

    float* out  = (float*)d_out;
    float* ctx  = out;          // [B, D]
    float* wout = out + B * D;  // [B, S, 1]

    float* ws     = (float*)d_ws;
    float* scores = ws;                 // B*S          = 65536
    float* cstats = scores + B * S;     // 2*B*NCHK     = 2048
    float* cpart  = cstats + 2048;      // B*NCHK*D     = 262144
    ushort* W1p   = (ushort*)(cpart + B * NCHK * D);  // 65536 ushorts

    ka_pack<<<8, 256, 0, stream>>>(W1, W1p);
    kb_scores<<<B * NCHK, 256, 0, stream>>>(values, W1p, query, W2, b2, b1, V, bV,
                                            scores, cstats, cpart);
    kc_final<<<B * 4, 256, 0, stream>>>(scores, cstats, cpart, wout, ctx);
}

// Round 23
// 42.514 us; speedup vs baseline: 1.2022x; 1.2022x over previous
//
#include <hip/hip_runtime.h>
#include <hip/hip_bf16.h>

#define B 16
#define S 4096
#define D 256
#define U 256
#define ROWS 64    // rows per block in score kernel
#define NCHK (S / ROWS)  // 64 chunks per batch

typedef short short8 __attribute__((ext_vector_type(8)));
typedef float f32x4 __attribute__((ext_vector_type(4)));

__device__ __forceinline__ ushort f2bf(float f) {
    union { float f; uint u; } x{f};
    uint r = (x.u + 0x7fffu + ((x.u >> 16) & 1u)) >> 16;  // RNE
    return (ushort)r;
}

__device__ __forceinline__ float fast_tanh(float x) {
    float e = __expf(2.0f * x);
    return 1.0f - 2.0f * __builtin_amdgcn_rcpf(e + 1.0f);
}

// KA: fused setup.
//  blocks 0..15 : pqb[b][u] = query[b,:].W2[:,u] + b2[u] + b1[u]
//  blocks 16..23: pack W1 (fp32 [D][U]) into bf16 MFMA B-fragment order, one kk each
__global__ void ka_setup(const float* __restrict__ q, const float* __restrict__ W2,
                         const float* __restrict__ b2, const float* __restrict__ b1,
                         const float* __restrict__ W1, float* __restrict__ pqb,
                         ushort* __restrict__ W1p) {
    int bid = blockIdx.x, t = threadIdx.x;
    if (bid < 16) {
        int b = bid, u = t;
        const float* qb = q + b * D;
        float acc = b2[u] + b1[u];
#pragma unroll 8
        for (int d = 0; d < D; ++d)
            acc = fmaf(qb[d], W2[d * U + u], acc);
        pqb[b * U + u] = acc;
    } else {
        int kk = bid - 16;
        int l = t & 63, g = t >> 6;
        int colu0 = l & 15;
        int k0 = kk * 32 + (l >> 4) * 8;
#pragma unroll
        for (int i = 0; i < 4; ++i) {
            int nt = g * 4 + i;
            int colu = nt * 16 + colu0;
            ushort* dst = W1p + (((nt * 8) + kk) * 64 + l) * 8;
#pragma unroll
            for (int e = 0; e < 8; ++e) dst[e] = f2bf(W1[(k0 + e) * U + colu]);
        }
    }
}

// KB: per 64-row chunk: scores via bf16 MFMA, chunk softmax stats (m_c, z_c),
// and unnormalized partial context from the bf16 LDS copy (single HBM pass).
__global__ __launch_bounds__(256, 4) void kb_scores(
    const float* __restrict__ values, const ushort* __restrict__ W1p,
    const float* __restrict__ pqb, const float* __restrict__ V,
    const float* __restrict__ bV, float* __restrict__ scores,
    float* __restrict__ cstats, float* __restrict__ cpart) {
    __shared__ ushort Alds[ROWS * 256];  // 32 KB, XOR-swizzled bf16 tile
    __shared__ float red[4][ROWS];
    __shared__ float wch[ROWS];
    int b = blockIdx.x >> 6;
    int s0 = (blockIdx.x & 63) * ROWS;
    int t = threadIdx.x;
    int w = t >> 6, l = t & 63;
    char* lds = (char*)Alds;

    // ---- stage 64x256 fp32 -> bf16 LDS, byte ^= (row&7)<<4 ----
    // Phase 1: issue ALL 16 float4 loads (64 VGPRs) so they overlap in flight.
    const float* src = values + ((size_t)(b * S + s0)) * D;
    float4 vreg[16];
#pragma unroll
    for (int i = 0; i < 16; ++i)
        vreg[i] = *(const float4*)&src[(i * 4 + w) * 256 + l * 4];
    // Phase 2: convert + swizzled LDS write.
#pragma unroll
    for (int i = 0; i < 16; ++i) {
        int row = i * 4 + w;
        int col = l * 4;
        ushort4 h;
        h.x = f2bf(vreg[i].x); h.y = f2bf(vreg[i].y);
        h.z = f2bf(vreg[i].z); h.w = f2bf(vreg[i].w);
        int byte = (row * 512 + col * 2) ^ ((row & 7) << 4);
        *(ushort4*)(lds + byte) = h;
    }
    __syncthreads();

    // ---- MFMA scores (kk fully unrolled) ----
    int lrow = l & 15, lk = l >> 4;
    f32x4 acc[4][4];
#pragma unroll
    for (int mt = 0; mt < 4; ++mt)
#pragma unroll
        for (int nt = 0; nt < 4; ++nt) acc[mt][nt] = (f32x4){0.f, 0.f, 0.f, 0.f};

#pragma unroll
    for (int kk = 0; kk < 8; ++kk) {
        short8 afr[4], bfr[4];
#pragma unroll
        for (int nt = 0; nt < 4; ++nt) {
            int ntile = w * 4 + nt;
            bfr[nt] = *(const short8*)&W1p[(((ntile * 8) + kk) * 64 + l) * 8];
        }
#pragma unroll
        for (int mt = 0; mt < 4; ++mt) {
            int row = mt * 16 + lrow;
            int byte = (row * 512 + kk * 64 + lk * 16) ^ ((row & 7) << 4);
            afr[mt] = *(const short8*)(lds + byte);
        }
#pragma unroll
        for (int mt = 0; mt < 4; ++mt)
#pragma unroll
            for (int nt = 0; nt < 4; ++nt)
                acc[mt][nt] = __builtin_amdgcn_mfma_f32_16x16x32_bf16(
                    afr[mt], bfr[nt], acc[mt][nt], 0, 0, 0);
    }

    // ---- epilogue: tanh, .V, reduce over u ----
    float bb[4], vv[4];
#pragma unroll
    for (int nt = 0; nt < 4; ++nt) {
        int u = (w * 4 + nt) * 16 + lrow;
        bb[nt] = pqb[b * U + u];
        vv[nt] = V[u];
    }
#pragma unroll
    for (int mt = 0; mt < 4; ++mt) {
#pragma unroll
        for (int r = 0; r < 4; ++r) {
            float s = 0.f;
#pragma unroll
            for (int nt = 0; nt < 4; ++nt)
                s += fast_tanh(acc[mt][nt][r] + bb[nt]) * vv[nt];
            s += __shfl_xor(s, 1);
            s += __shfl_xor(s, 2);
            s += __shfl_xor(s, 4);
            s += __shfl_xor(s, 8);
            if (lrow == 0) red[w][mt * 16 + lk * 4 + r] = s;
        }
    }
    __syncthreads();
    if (t < ROWS) {  // wave 0
        float s = red[0][t] + red[1][t] + red[2][t] + red[3][t] + bV[0];
        scores[b * S + s0 + t] = s;
        float m = s;
#pragma unroll
        for (int off = 32; off; off >>= 1) m = fmaxf(m, __shfl_xor(m, off));
        float z0 = __expf(s - m);
        wch[t] = z0;
        float z = z0;
#pragma unroll
        for (int off = 32; off; off >>= 1) z += __shfl_xor(z, off);
        if (t == 0) {
            cstats[2 * blockIdx.x] = m;
            cstats[2 * blockIdx.x + 1] = z;
        }
    }
    __syncthreads();

    // partial context from the bf16 LDS copy: thread t owns column t.
    union { uint i; float f; } cv;
    float cacc = 0.f;
#pragma unroll 8
    for (int r = 0; r < ROWS; ++r) {
        int byte = (r * 512 + t * 2) ^ ((r & 7) << 4);
        ushort u = *(const ushort*)(lds + byte);
        cv.i = (uint)u << 16;
        cacc = fmaf(wch[r], cv.f, cacc);
    }
    cpart[(size_t)blockIdx.x * D + t] = cacc;
}

// KC: finisher. 4 blocks per batch (q = quarter).
__global__ void kc_final(const float* __restrict__ scores, const float* __restrict__ cstats,
                         const float* __restrict__ cpart, float* __restrict__ wout,
                         float* __restrict__ ctx) {
    __shared__ float scl[NCHK];
    __shared__ float stats[2];
    __shared__ float part[4][64];
    int b = blockIdx.x >> 2, q = blockIdx.x & 3;
    int t = threadIdx.x;

    if (t < 64) {
        float m = cstats[2 * (b * NCHK + t)];
        float z = cstats[2 * (b * NCHK + t) + 1];
        float M = m;
#pragma unroll
        for (int off = 32; off; off >>= 1) M = fmaxf(M, __shfl_xor(M, off));
        float zz = z * __expf(m - M);
#pragma unroll
        for (int off = 32; off; off >>= 1) zz += __shfl_xor(zz, off);
        scl[t] = __expf(m - M);
        if (t == 0) { stats[0] = M; stats[1] = zz; }
    }
    __syncthreads();
    float M = stats[0];
    float invZ = 1.0f / stats[1];

    int tq = t >> 6, dl = t & 63;
    int d = q * 64 + dl;
    float acc = 0.f;
#pragma unroll
    for (int i = 0; i < 16; ++i) {
        int c = tq * 16 + i;
        acc = fmaf(scl[c], cpart[(size_t)(b * NCHK + c) * D + d], acc);
    }
    part[tq][dl] = acc;

#pragma unroll
    for (int i = 0; i < 4; ++i) {
        int s = q * 1024 + i * 256 + t;
        wout[b * S + s] = __expf(scores[b * S + s] - M) * invZ;
    }
    __syncthreads();
    if (t < 64)
        ctx[b * D + q * 64 + t] =
            (part[0][t] + part[1][t] + part[2][t] + part[3][t]) * invZ;
}

extern "C" void kernel_launch(void* const* d_in, const int* in_sizes, int n_in,
                              void* d_out, int out_size, void* d_ws, size_t ws_size,
                              hipStream_t stream) {
    const float* values = (const float*)d_in[0];
    const float* query  = (const float*)d_in[1];
    const float* W1     = (const float*)d_in[2];
    const float* b1     = (const float*)d_in[3];
    const float* W2     = (const float*)d_in[4];
    const float* b2     = (const float*)d_in[5];
    const float* V      = (const float*)d_in[6];
    const float* bV     = (const float*)d_in[7];

    float* out  = (float*)d_out;
    float* ctx  = out;          // [B, D]
    float* wout = out + B * D;  // [B, S, 1]

    float* ws     = (float*)d_ws;
    float* pqb    = ws;                 // B*U          = 4096
    float* scores = pqb + B * U;        // B*S          = 65536
    float* cstats = scores + B * S;     // 2*B*NCHK     = 2048
    float* cpart  = cstats + 2048;      // B*NCHK*D     = 262144
    ushort* W1p   = (ushort*)(cpart + B * NCHK * D);  // 65536 ushorts

    ka_setup<<<24, 256, 0, stream>>>(query, W2, b2, b1, W1, pqb, W1p);
    kb_scores<<<B * NCHK, 256, 0, stream>>>(values, W1p, pqb, V, bV, scores, cstats, cpart);
    kc_final<<<B * 4, 256, 0, stream>>>(scores, cstats, cpart, wout, ctx);
}